// Round 11
// baseline (227.104 us; speedup 1.0000x reference)
//
#include <hip/hip_runtime.h>

typedef __bf16 bf16;
typedef __bf16 bf16x4 __attribute__((ext_vector_type(4)));
typedef __bf16 bf16x8 __attribute__((ext_vector_type(8)));
typedef float  f32x4  __attribute__((ext_vector_type(4)));
typedef float  f32x16 __attribute__((ext_vector_type(16)));

#define T_DIM 256
#define B_DIM 256
#define NIN   512
#define NH    512
#define NEMB  256
#define NX    768      // NIN + NEMB
#define NG    1536     // 3*NH
#define MTOT  65536    // T*B

__device__ __forceinline__ float fast_tanh(float x) {
    float e = __expf(2.0f * x);
    return 1.0f - 2.0f * __builtin_amdgcn_rcpf(e + 1.0f);
}
__device__ __forceinline__ float fast_sigmoid(float x) {
    return __builtin_amdgcn_rcpf(1.0f + __expf(-x));
}

// ---------------- weight/h conversion; w_i2h -> frag-major Wfrag (v9 layout) ----------
// Wfrag[((g*32+ks)*64 + lane)*8 + j] = w_i2h[g*32+(lane&31)][ks*16+(lane>>5)*8+j]
__global__ __launch_bounds__(256) void cvt_weights(
    const float* __restrict__ a0, const float* __restrict__ a1,
    const float* __restrict__ a2, const float* __restrict__ a3,
    const float* __restrict__ a4,
    bf16* __restrict__ b0, bf16* __restrict__ b1, bf16* __restrict__ b2,
    bf16* __restrict__ b3, bf16* __restrict__ b4) {
    const int N0 = 65536, N1 = 131072, N2 = 425984, N3 = 622592, N4 = 655360;
    for (int i = blockIdx.x * 256 + threadIdx.x; i < N4; i += gridDim.x * 256) {
        const float* s; bf16* d; int j; bool img = false;
        if (i < N0)      { s = a0; d = b0; j = i; img = true; }
        else if (i < N1) { s = a1; d = b1; j = i - N0; }
        else if (i < N2) { s = a2; d = b2; j = i - N1; }
        else if (i < N3) { s = a3; d = b3; j = i - N2; }
        else             { s = a4; d = b4; j = i - N3; }
        float4 v = reinterpret_cast<const float4*>(s)[j];
        bf16x4 o = { (bf16)v.x, (bf16)v.y, (bf16)v.z, (bf16)v.w };
        if (img) {
            int e = j * 4, col = e >> 9, K = e & 511;
            int g = col >> 5, cl = col & 31;
            int ks = K >> 4, kh = (K >> 3) & 1, j0 = K & 7;
            int lane = kh * 32 + cl;
            int off = (((g * 32 + ks) * 64) + lane) * 8 + j0;
            *reinterpret_cast<bf16x4*>(d + off) = o;
        } else {
            reinterpret_cast<bf16x4*>(d)[j] = o;
        }
    }
}

// ---------------- generic GEMM: C = A*B^T + bias; optional transposed C-write --------
__global__ __launch_bounds__(256) void gemm_bias(
    const bf16* __restrict__ A, const bf16* __restrict__ B,
    const float* __restrict__ bias, float* __restrict__ C,
    int M, int N, int K, int transC) {
    __shared__ bf16 At[64][40];
    __shared__ bf16 Bt[64][40];
    const int tid = threadIdx.x;
    const int m0 = blockIdx.y * 64, n0 = blockIdx.x * 64;
    const int wid = tid >> 6, lane = tid & 63, hi = lane >> 4, lo = lane & 15;
    const int srow = tid >> 2, sseg = tid & 3;
    f32x4 acc[4] = {};

    for (int kk = 0; kk < K; kk += 32) {
        bf16x8 av = *reinterpret_cast<const bf16x8*>(A + (size_t)(m0 + srow) * K + kk + sseg * 8);
        bf16x8 bv = *reinterpret_cast<const bf16x8*>(B + (size_t)(n0 + srow) * K + kk + sseg * 8);
        __syncthreads();
        *reinterpret_cast<bf16x8*>(&At[srow][sseg * 8]) = av;
        *reinterpret_cast<bf16x8*>(&Bt[srow][sseg * 8]) = bv;
        __syncthreads();
        bf16x8 a = *reinterpret_cast<const bf16x8*>(&At[wid * 16 + lo][hi * 8]);
#pragma unroll
        for (int nt = 0; nt < 4; ++nt) {
            bf16x8 b = *reinterpret_cast<const bf16x8*>(&Bt[nt * 16 + lo][hi * 8]);
            acc[nt] = __builtin_amdgcn_mfma_f32_16x16x32_bf16(a, b, acc[nt], 0, 0, 0);
        }
    }
#pragma unroll
    for (int nt = 0; nt < 4; ++nt) {
        int n = n0 + nt * 16 + lo;
        float bv = bias[n];
#pragma unroll
        for (int r = 0; r < 4; ++r) {
            int m = m0 + wid * 16 + hi * 4 + r;
            if (transC) C[(size_t)n * M + m] = acc[nt][r] + bv;
            else        C[(size_t)m * N + n] = acc[nt][r] + bv;
        }
    }
}

// ---------------- fused emit kernel (v10: swapped operands, lane-local n-reduce) ------
// D[n][m] = W·feats^T; W persistent in VGPRs (A-operand); feats frags via LDS (B-op).
// 256 blocks = 2 n-slabs x 128 m-chunks; 8 waves x 32 cols; 16 windows of 32 m-rows.
// Per window/wave: 32 b128 LDS reads + 32 MFMA; epilogue = in-lane sum + ONE shfl.
__global__ __launch_bounds__(512, 2) void emit_kernel(
    const float* __restrict__ feats, const bf16* __restrict__ Wfrag,
    const float* __restrict__ hT, const float* __restrict__ wscore,
    float* __restrict__ emit_part) {
    __shared__ bf16 Alds[2][32 * 512];   // 64 KB dbuf, chunk-XOR swizzled
    __shared__ float ew[2][8][32];
    const int tid = threadIdx.x;
    const int wid = tid >> 6, lane = tid & 63;
    const int half = lane >> 5, l31 = lane & 31;
    const int slab = blockIdx.x & 1, mchunk = blockIdx.x >> 1;
    const size_t m0 = (size_t)mchunk * 512;
    const int n0w = slab * 256 + wid * 32;

    // ---- persistent W frags (A-operand), 128 VGPR ----
    const bf16* wsrc = Wfrag + (size_t)((slab * 8 + wid) * 32) * 512 + lane * 8;
    bf16x8 wfr[32];
#pragma unroll
    for (int ks = 0; ks < 32; ++ks)
        wfr[ks] = *reinterpret_cast<const bf16x8*>(wsrc + ks * 512);

    // w_score for this lane's 16 n-rows
    float wsr[16];
#pragma unroll
    for (int r = 0; r < 16; ++r)
        wsr[r] = wscore[n0w + (r & 3) + 8 * (r >> 2) + 4 * half];

    // ---- A staging map: thread covers 4 chunks (i*8+sr, scc) ----
    const int sr = tid >> 6, scc = tid & 63;
    const float* abase = feats + (m0 + sr) * NIN + scc * 8;
    const int adst = ((scc ^ sr) << 3);   // chunk XOR by row (sr = row&7)

    float4 va[8];
#pragma unroll
    for (int i = 0; i < 4; ++i) {
        const float* p = abase + (size_t)i * 8 * NIN;
        va[2 * i]     = *reinterpret_cast<const float4*>(p);
        va[2 * i + 1] = *reinterpret_cast<const float4*>(p + 4);
    }
#pragma unroll
    for (int i = 0; i < 4; ++i) {
        bf16x8 o = { (bf16)va[2*i].x, (bf16)va[2*i].y, (bf16)va[2*i].z, (bf16)va[2*i].w,
                     (bf16)va[2*i+1].x, (bf16)va[2*i+1].y, (bf16)va[2*i+1].z, (bf16)va[2*i+1].w };
        *reinterpret_cast<bf16x8*>(&Alds[0][(i * 8 + sr) * 512 + adst]) = o;
    }
    __syncthreads();

    const int arow = l31 * 512, axor = (l31 & 7);
    for (int it = 0; it < 16; ++it) {
        const int cur = it & 1;
        // issue A(it+1) f32 loads; the ~3k-cycle window covers HBM latency
        if (it < 15) {
#pragma unroll
            for (int i = 0; i < 4; ++i) {
                const float* p = abase + (size_t)((it + 1) * 32 + i * 8) * NIN;
                va[2 * i]     = *reinterpret_cast<const float4*>(p);
                va[2 * i + 1] = *reinterpret_cast<const float4*>(p + 4);
            }
        }
        // store previous window's emit rows (wave0)
        if (it > 0 && tid < 32) {
            float s = 0.0f;
#pragma unroll
            for (int w = 0; w < 8; ++w) s += ew[cur ^ 1][w][tid];
            emit_part[(size_t)slab * MTOT + m0 + (it - 1) * 32 + tid] = s;
        }

        // ---- 32 MFMA: A=wfr (regs), B=feats frag (1 b128 read each) ----
        f32x16 acc0 = {}, acc1 = {};
        const bf16* ab = &Alds[cur][0];
#pragma unroll
        for (int ks = 0; ks < 32; ks += 2) {
            bf16x8 f0 = *reinterpret_cast<const bf16x8*>(
                ab + arow + (((2 * ks + half) ^ axor) << 3));
            acc0 = __builtin_amdgcn_mfma_f32_32x32x16_bf16(wfr[ks], f0, acc0, 0, 0, 0);
            bf16x8 f1 = *reinterpret_cast<const bf16x8*>(
                ab + arow + (((2 * ks + 2 + half) ^ axor) << 3));
            acc1 = __builtin_amdgcn_mfma_f32_32x32x16_bf16(wfr[ks + 1], f1, acc1, 0, 0, 0);
        }

        // ---- epilogue: lane-local n-sum (+ one half-swap) ----
        float e = 0.0f;
        const int bcol = (it * 32 + l31) & (B_DIM - 1);
#pragma unroll
        for (int r = 0; r < 16; ++r) {
            int nr = (r & 3) + 8 * (r >> 2) + 4 * half;
            float hv = hT[(size_t)(n0w + nr) * B_DIM + bcol];
            e += fast_tanh(acc0[r] + acc1[r] + hv) * wsr[r];
        }
        e += __shfl_xor(e, 32, 64);
        if (lane < 32) ew[cur][wid][l31] = e;

        // ---- stage A(it+1) ----
        if (it < 15) {
#pragma unroll
            for (int i = 0; i < 4; ++i) {
                bf16x8 o = { (bf16)va[2*i].x, (bf16)va[2*i].y, (bf16)va[2*i].z, (bf16)va[2*i].w,
                             (bf16)va[2*i+1].x, (bf16)va[2*i+1].y, (bf16)va[2*i+1].z, (bf16)va[2*i+1].w };
                *reinterpret_cast<bf16x8*>(&Alds[cur ^ 1][(i * 8 + sr) * 512 + adst]) = o;
            }
        }
        __syncthreads();
    }
    // last window's store
    if (tid < 32) {
        float s = 0.0f;
#pragma unroll
        for (int w = 0; w < 8; ++w) s += ew[1][w][tid];
        emit_part[(size_t)slab * MTOT + m0 + 15 * 32 + tid] = s;
    }
}

// ---------------- softmax over T (per column b), summing 2 slab partials --------------
__global__ __launch_bounds__(256) void softmax_t(
    const float* __restrict__ emit_part, float* __restrict__ alpha,
    float* __restrict__ out_alpha) {
    int b = blockIdx.x, t = threadIdx.x;
    int wv = t >> 6, ln = t & 63;
    size_t m = (size_t)t * B_DIM + b;
    float e = emit_part[m] + emit_part[MTOT + m];
    float mx = e;
#pragma unroll
    for (int off = 32; off; off >>= 1) mx = fmaxf(mx, __shfl_xor(mx, off, 64));
    __shared__ float red[4], red2[4];
    if (ln == 0) red[wv] = mx;
    __syncthreads();
    mx = fmaxf(fmaxf(red[0], red[1]), fmaxf(red[2], red[3]));
    float p = __expf(e - mx);
    float s = p;
#pragma unroll
    for (int off = 32; off; off >>= 1) s += __shfl_xor(s, off, 64);
    if (ln == 0) red2[wv] = s;
    __syncthreads();
    float inv = __builtin_amdgcn_rcpf(red2[0] + red2[1] + red2[2] + red2[3]);
    float a = p * inv;
    alpha[m] = a;
    out_alpha[m] = a;
}

// ---------------- context + build_x fused (reads f32 feats, L3-resident) --------------
__global__ __launch_bounds__(256) void ctx_kernel(
    const float* __restrict__ feats, const float* __restrict__ alpha,
    const float* __restrict__ emb, bf16* __restrict__ x) {
    int b = blockIdx.x;
    __shared__ float al[T_DIM];
    __shared__ float red[4][512];
    int tid = threadIdx.x;
    al[tid] = alpha[(size_t)tid * B_DIM + b];
    __syncthreads();
    int c8 = tid & 63, tq = tid >> 6;
    float acc[8] = {};
#pragma unroll 4
    for (int t = tq * 64; t < tq * 64 + 64; ++t) {
        const float* src = feats + ((size_t)(t * B_DIM + b)) * NIN + c8 * 8;
        float4 v0 = *reinterpret_cast<const float4*>(src);
        float4 v1 = *reinterpret_cast<const float4*>(src + 4);
        float a = al[t];
        acc[0] += a * v0.x; acc[1] += a * v0.y; acc[2] += a * v0.z; acc[3] += a * v0.w;
        acc[4] += a * v1.x; acc[5] += a * v1.y; acc[6] += a * v1.z; acc[7] += a * v1.w;
    }
#pragma unroll
    for (int j = 0; j < 8; ++j) red[tq][c8 * 8 + j] = acc[j];
    __syncthreads();
#pragma unroll
    for (int k = 0; k < 2; ++k) {
        int c = tid * 2 + k;
        float s = red[0][c] + red[1][c] + red[2][c] + red[3][c];
        x[(size_t)b * NX + c] = (bf16)s;
    }
    x[(size_t)b * NX + NIN + tid] = (bf16)emb[(size_t)b * NEMB + tid];
}

// ---------------- GRU gates ----------------
__global__ __launch_bounds__(256) void gru_kernel(
    const float* __restrict__ gi, const float* __restrict__ gh,
    const float* __restrict__ h, float* __restrict__ out) {
    int idx = blockIdx.x * 256 + threadIdx.x;
    int b = idx >> 9, j = idx & 511;
    const float* gib = gi + (size_t)b * NG;
    const float* ghb = gh + (size_t)b * NG;
    float r = fast_sigmoid(gib[j] + ghb[j]);
    float z = fast_sigmoid(gib[NH + j] + ghb[NH + j]);
    float n = fast_tanh(gib[2 * NH + j] + r * ghb[2 * NH + j]);
    out[idx] = (1.0f - z) * n + z * h[idx];
}

extern "C" void kernel_launch(void* const* d_in, const int* in_sizes, int n_in,
                              void* d_out, int out_size, void* d_ws, size_t ws_size,
                              hipStream_t stream) {
    const float* feats = (const float*)d_in[0];
    const float* h     = (const float*)d_in[1];
    const float* emb   = (const float*)d_in[2];
    const float* w_i2h = (const float*)d_in[3];
    const float* w_h2h = (const float*)d_in[4];
    const float* b_h2h = (const float*)d_in[5];
    const float* w_sc  = (const float*)d_in[6];
    const float* w_ih  = (const float*)d_in[7];
    const float* w_hh  = (const float*)d_in[8];
    const float* b_ih  = (const float*)d_in[9];
    const float* b_hh  = (const float*)d_in[10];
    float* out = (float*)d_out;

    char* ws = (char*)d_ws;
    bf16*  Wfrag   = (bf16*)(ws);                 // 524288 (frag-major image)
    bf16*  w_h2h_b = (bf16*)(ws + 524288);        // 524288
    bf16*  w_ih_b  = (bf16*)(ws + 1048576);       // 2359296
    bf16*  w_hh_b  = (bf16*)(ws + 3407872);       // 1572864
    bf16*  h_b     = (bf16*)(ws + 4980736);       // 262144
    bf16*  x_b     = (bf16*)(ws + 5242880);       // 393216
    float* hT      = (float*)(ws + 5636096);      // 524288 (h_ transposed [512][256])
    float* emit_p  = (float*)(ws + 6160384);      // 524288 (2 slab partials)
    float* alpha   = (float*)(ws + 6684672);      // 262144
    float* gi      = (float*)(ws + 6946816);      // 1572864
    float* gh      = (float*)(ws + 8519680);      // 1572864  -> total 10092544

    // 1) weight/h conversions (w_i2h -> frag-major Wfrag)
    cvt_weights<<<1024, 256, 0, stream>>>(w_i2h, w_h2h, w_ih, w_hh, h,
                                          Wfrag, w_h2h_b, w_ih_b, w_hh_b, h_b);

    // 2) hT = (h @ w_h2h^T + b_h2h)^T ; gh = h @ w_hh^T + b_hh
    gemm_bias<<<dim3(8, 4), 256, 0, stream>>>(h_b, w_h2h_b, b_h2h, hT, 256, NH, NH, 1);
    gemm_bias<<<dim3(24, 4), 256, 0, stream>>>(h_b, w_hh_b, b_hh, gh, 256, NG, NH, 0);

    // 3) fused emit (swapped-operand structure)
    emit_kernel<<<256, 512, 0, stream>>>(feats, Wfrag, hT, w_sc, emit_p);

    // 4) alpha = softmax_T(sum of 2 partials); also output 1
    softmax_t<<<256, 256, 0, stream>>>(emit_p, alpha, out + 131072);

    // 5) context + x build (fused, f32 feats from L3)
    ctx_kernel<<<256, 256, 0, stream>>>(feats, alpha, emb, x_b);

    // 6) gi = x @ w_ih^T + b_ih
    gemm_bias<<<dim3(24, 4), 256, 0, stream>>>(x_b, w_ih_b, b_ih, gi, 256, NG, NX, 0);

    // 7) GRU -> nh (output 0)
    gru_kernel<<<512, 256, 0, stream>>>(gi, gh, h, out);
}

// Round 12
// 224.459 us; speedup vs baseline: 1.0118x; 1.0118x over previous
//
#include <hip/hip_runtime.h>

typedef __bf16 bf16;
typedef __bf16 bf16x4 __attribute__((ext_vector_type(4)));
typedef __bf16 bf16x8 __attribute__((ext_vector_type(8)));
typedef float  f32x4  __attribute__((ext_vector_type(4)));
typedef float  f32x16 __attribute__((ext_vector_type(16)));

#define T_DIM 256
#define B_DIM 256
#define NIN   512
#define NH    512
#define NEMB  256
#define NX    768      // NIN + NEMB
#define NG    1536     // 3*NH
#define MTOT  65536    // T*B

__device__ __forceinline__ float fast_tanh(float x) {
    float e = __expf(2.0f * x);
    return 1.0f - 2.0f * __builtin_amdgcn_rcpf(e + 1.0f);
}
__device__ __forceinline__ float fast_sigmoid(float x) {
    return __builtin_amdgcn_rcpf(1.0f + __expf(-x));
}

__device__ __forceinline__ void gload_lds16f(const float* g, float* l) {
    __builtin_amdgcn_global_load_lds(
        (const __attribute__((address_space(1))) void*)g,
        (__attribute__((address_space(3))) void*)l, 16, 0, 0);
}

// ---------------- weight/h conversion; w_i2h -> frag-major Wfrag (v9/v10 verified) ----
// Wfrag[((g*32+ks)*64 + lane)*8 + j] = w_i2h[g*32+(lane&31)][ks*16+(lane>>5)*8+j]
__global__ __launch_bounds__(256) void cvt_weights(
    const float* __restrict__ a0, const float* __restrict__ a1,
    const float* __restrict__ a2, const float* __restrict__ a3,
    const float* __restrict__ a4,
    bf16* __restrict__ b0, bf16* __restrict__ b1, bf16* __restrict__ b2,
    bf16* __restrict__ b3, bf16* __restrict__ b4) {
    const int N0 = 65536, N1 = 131072, N2 = 425984, N3 = 622592, N4 = 655360;
    for (int i = blockIdx.x * 256 + threadIdx.x; i < N4; i += gridDim.x * 256) {
        const float* s; bf16* d; int j; bool img = false;
        if (i < N0)      { s = a0; d = b0; j = i; img = true; }
        else if (i < N1) { s = a1; d = b1; j = i - N0; }
        else if (i < N2) { s = a2; d = b2; j = i - N1; }
        else if (i < N3) { s = a3; d = b3; j = i - N2; }
        else             { s = a4; d = b4; j = i - N3; }
        float4 v = reinterpret_cast<const float4*>(s)[j];
        bf16x4 o = { (bf16)v.x, (bf16)v.y, (bf16)v.z, (bf16)v.w };
        if (img) {
            int e = j * 4, col = e >> 9, K = e & 511;
            int g = col >> 5, cl = col & 31;
            int ks = K >> 4, kh = (K >> 3) & 1, j0 = K & 7;
            int lane = kh * 32 + cl;
            int off = (((g * 32 + ks) * 64) + lane) * 8 + j0;
            *reinterpret_cast<bf16x4*>(d + off) = o;
        } else {
            reinterpret_cast<bf16x4*>(d)[j] = o;
        }
    }
}

// ---------------- generic GEMM: C = A*B^T + bias; optional transposed C-write --------
__global__ __launch_bounds__(256) void gemm_bias(
    const bf16* __restrict__ A, const bf16* __restrict__ B,
    const float* __restrict__ bias, float* __restrict__ C,
    int M, int N, int K, int transC) {
    __shared__ bf16 At[64][40];
    __shared__ bf16 Bt[64][40];
    const int tid = threadIdx.x;
    const int m0 = blockIdx.y * 64, n0 = blockIdx.x * 64;
    const int wid = tid >> 6, lane = tid & 63, hi = lane >> 4, lo = lane & 15;
    const int srow = tid >> 2, sseg = tid & 3;
    f32x4 acc[4] = {};

    for (int kk = 0; kk < K; kk += 32) {
        bf16x8 av = *reinterpret_cast<const bf16x8*>(A + (size_t)(m0 + srow) * K + kk + sseg * 8);
        bf16x8 bv = *reinterpret_cast<const bf16x8*>(B + (size_t)(n0 + srow) * K + kk + sseg * 8);
        __syncthreads();
        *reinterpret_cast<bf16x8*>(&At[srow][sseg * 8]) = av;
        *reinterpret_cast<bf16x8*>(&Bt[srow][sseg * 8]) = bv;
        __syncthreads();
        bf16x8 a = *reinterpret_cast<const bf16x8*>(&At[wid * 16 + lo][hi * 8]);
#pragma unroll
        for (int nt = 0; nt < 4; ++nt) {
            bf16x8 b = *reinterpret_cast<const bf16x8*>(&Bt[nt * 16 + lo][hi * 8]);
            acc[nt] = __builtin_amdgcn_mfma_f32_16x16x32_bf16(a, b, acc[nt], 0, 0, 0);
        }
    }
#pragma unroll
    for (int nt = 0; nt < 4; ++nt) {
        int n = n0 + nt * 16 + lo;
        float bv = bias[n];
#pragma unroll
        for (int r = 0; r < 4; ++r) {
            int m = m0 + wid * 16 + hi * 4 + r;
            if (transC) C[(size_t)n * M + m] = acc[nt][r] + bv;
            else        C[(size_t)m * N + n] = acc[nt][r] + bv;
        }
    }
}

// ---------------- fused emit kernel (v11: swapped operands, f32 DMA windows) ----------
// D[n][m] = W·feats^T. W persistent in VGPRs (A-operand, 128 VGPR).
// feats: 32-row f32 windows DMA'd via global_load_lds into a 2x64KB LDS ring,
// 16B-slot XOR swizzle (slot = q ^ row), source pre-swizzled per rule 21.
// Epilogue: lane-local n-reduce + ONE shfl (v10-verified).
// Grid: 256 blocks, XCD-paired so slab pairs share an XCD's L2.
__global__ __launch_bounds__(512, 2) void emit_kernel(
    const float* __restrict__ feats, const bf16* __restrict__ Wfrag,
    const float* __restrict__ hT, const float* __restrict__ wscore,
    float* __restrict__ emit_part) {
    __shared__ float Awin[2][32 * 512];   // 2 x 64 KB f32 windows
    __shared__ float ew[2][8][32];
    const int tid = threadIdx.x;
    const int wid = tid >> 6, lane = tid & 63;
    const int half = lane >> 5, l31 = lane & 31;
    // XCD-paired task map: tasks on xcd are consecutive; (slab0,slab1) pairs co-resident
    const int task = (blockIdx.x & 7) * 32 + (blockIdx.x >> 3);
    const int slab = task & 1, mchunk = task >> 1;      // mchunk 0..127
    const size_t m0 = (size_t)mchunk * 512;
    const int n0w = slab * 256 + wid * 32;

    // ---- persistent W frags (A-operand) ----
    const bf16* wsrc = Wfrag + (size_t)((slab * 8 + wid) * 32) * 512 + lane * 8;
    bf16x8 wfr[32];
#pragma unroll
    for (int ks = 0; ks < 32; ++ks)
        wfr[ks] = *reinterpret_cast<const bf16x8*>(wsrc + ks * 512);

    float wsr[16];
#pragma unroll
    for (int r = 0; r < 16; ++r)
        wsr[r] = wscore[n0w + (r & 3) + 8 * (r >> 2) + 4 * half];

    // ---- DMA staging: 64 instrs/window; wave wid issues d = wid*8+i ----
    // dest (linear): Awin[buf] + d*256 floats (+ lane*16B by HW)
    // src (inverse-swizzled): row r = d>>1; q = (d&1)*64 + (lane ^ r); byte = q*16
#define STAGE_WINDOW(buf, w)                                                      \
    {                                                                             \
        _Pragma("unroll")                                                         \
        for (int i = 0; i < 8; ++i) {                                             \
            int d = wid * 8 + i;                                                  \
            int r = d >> 1;                                                       \
            const float* src = feats + (m0 + (size_t)(w) * 32 + r) * NIN          \
                               + (((d & 1) << 6) + (lane ^ r)) * 4;               \
            gload_lds16f(src, &Awin[buf][d * 256]);                               \
        }                                                                         \
    }

    STAGE_WINDOW(0, 0)
    __syncthreads();

    f32x16 acc0, acc1;
    const float* rowp0 = &Awin[0][l31 * 512];
    const float* rowp1 = &Awin[1][l31 * 512];

    for (int it = 0; it < 16; ++it) {
        const int cur = it & 1;
        // DMA next window into the other buffer (its readers finished last barrier)
        if (it < 15) {
            if (cur) STAGE_WINDOW(0, it + 1)
            else     STAGE_WINDOW(1, it + 1)
        }
        // store previous window's emit rows
        if (it > 0 && tid < 32) {
            float s = 0.0f;
#pragma unroll
            for (int w = 0; w < 8; ++w) s += ew[cur ^ 1][w][tid];
            emit_part[(size_t)slab * MTOT + m0 + (it - 1) * 32 + tid] = s;
        }

        // ---- 32 MFMA: A = wfr (regs), B = feats frag (2 b128 f32 reads + cvt) ----
        acc0 = (f32x16){}; acc1 = (f32x16){};
        const float* rowp = cur ? rowp1 : rowp0;
#pragma unroll
        for (int ks = 0; ks < 32; ks += 2) {
            int q0 = ks * 4 + half * 2;
            f32x4 u0 = *reinterpret_cast<const f32x4*>(rowp + ((q0 ^ l31) << 2));
            f32x4 u1 = *reinterpret_cast<const f32x4*>(rowp + (((q0 + 1) ^ l31) << 2));
            bf16x8 f0 = { (bf16)u0[0], (bf16)u0[1], (bf16)u0[2], (bf16)u0[3],
                          (bf16)u1[0], (bf16)u1[1], (bf16)u1[2], (bf16)u1[3] };
            acc0 = __builtin_amdgcn_mfma_f32_32x32x16_bf16(wfr[ks], f0, acc0, 0, 0, 0);
            int q2 = q0 + 4;
            f32x4 u2 = *reinterpret_cast<const f32x4*>(rowp + ((q2 ^ l31) << 2));
            f32x4 u3 = *reinterpret_cast<const f32x4*>(rowp + (((q2 + 1) ^ l31) << 2));
            bf16x8 f1 = { (bf16)u2[0], (bf16)u2[1], (bf16)u2[2], (bf16)u2[3],
                          (bf16)u3[0], (bf16)u3[1], (bf16)u3[2], (bf16)u3[3] };
            acc1 = __builtin_amdgcn_mfma_f32_32x32x16_bf16(wfr[ks + 1], f1, acc1, 0, 0, 0);
        }

        // ---- epilogue: lane-local n-sum + one half-swap (v10-verified) ----
        float e = 0.0f;
        const int bcol = (it * 32 + l31) & (B_DIM - 1);
#pragma unroll
        for (int r = 0; r < 16; ++r) {
            int nr = (r & 3) + 8 * (r >> 2) + 4 * half;
            float hv = hT[(size_t)(n0w + nr) * B_DIM + bcol];
            e += fast_tanh(acc0[r] + acc1[r] + hv) * wsr[r];
        }
        e += __shfl_xor(e, 32, 64);
        if (lane < 32) ew[cur][wid][l31] = e;

        __syncthreads();   // drains next-window DMA; publishes ew[cur]
    }
    // last window's store
    if (tid < 32) {
        float s = 0.0f;
#pragma unroll
        for (int w = 0; w < 8; ++w) s += ew[1][w][tid];
        emit_part[(size_t)slab * MTOT + m0 + 15 * 32 + tid] = s;
    }
#undef STAGE_WINDOW
}

// ---------------- softmax over T (per column b), summing 2 slab partials --------------
__global__ __launch_bounds__(256) void softmax_t(
    const float* __restrict__ emit_part, float* __restrict__ alpha,
    float* __restrict__ out_alpha) {
    int b = blockIdx.x, t = threadIdx.x;
    int wv = t >> 6, ln = t & 63;
    size_t m = (size_t)t * B_DIM + b;
    float e = emit_part[m] + emit_part[MTOT + m];
    float mx = e;
#pragma unroll
    for (int off = 32; off; off >>= 1) mx = fmaxf(mx, __shfl_xor(mx, off, 64));
    __shared__ float red[4], red2[4];
    if (ln == 0) red[wv] = mx;
    __syncthreads();
    mx = fmaxf(fmaxf(red[0], red[1]), fmaxf(red[2], red[3]));
    float p = __expf(e - mx);
    float s = p;
#pragma unroll
    for (int off = 32; off; off >>= 1) s += __shfl_xor(s, off, 64);
    if (ln == 0) red2[wv] = s;
    __syncthreads();
    float inv = __builtin_amdgcn_rcpf(red2[0] + red2[1] + red2[2] + red2[3]);
    float a = p * inv;
    alpha[m] = a;
    out_alpha[m] = a;
}

// ---------------- context + build_x fused (reads f32 feats, L3-resident) --------------
__global__ __launch_bounds__(256) void ctx_kernel(
    const float* __restrict__ feats, const float* __restrict__ alpha,
    const float* __restrict__ emb, bf16* __restrict__ x) {
    int b = blockIdx.x;
    __shared__ float al[T_DIM];
    __shared__ float red[4][512];
    int tid = threadIdx.x;
    al[tid] = alpha[(size_t)tid * B_DIM + b];
    __syncthreads();
    int c8 = tid & 63, tq = tid >> 6;
    float acc[8] = {};
#pragma unroll 4
    for (int t = tq * 64; t < tq * 64 + 64; ++t) {
        const float* src = feats + ((size_t)(t * B_DIM + b)) * NIN + c8 * 8;
        float4 v0 = *reinterpret_cast<const float4*>(src);
        float4 v1 = *reinterpret_cast<const float4*>(src + 4);
        float a = al[t];
        acc[0] += a * v0.x; acc[1] += a * v0.y; acc[2] += a * v0.z; acc[3] += a * v0.w;
        acc[4] += a * v1.x; acc[5] += a * v1.y; acc[6] += a * v1.z; acc[7] += a * v1.w;
    }
#pragma unroll
    for (int j = 0; j < 8; ++j) red[tq][c8 * 8 + j] = acc[j];
    __syncthreads();
#pragma unroll
    for (int k = 0; k < 2; ++k) {
        int c = tid * 2 + k;
        float s = red[0][c] + red[1][c] + red[2][c] + red[3][c];
        x[(size_t)b * NX + c] = (bf16)s;
    }
    x[(size_t)b * NX + NIN + tid] = (bf16)emb[(size_t)b * NEMB + tid];
}

// ---------------- GRU gates ----------------
__global__ __launch_bounds__(256) void gru_kernel(
    const float* __restrict__ gi, const float* __restrict__ gh,
    const float* __restrict__ h, float* __restrict__ out) {
    int idx = blockIdx.x * 256 + threadIdx.x;
    int b = idx >> 9, j = idx & 511;
    const float* gib = gi + (size_t)b * NG;
    const float* ghb = gh + (size_t)b * NG;
    float r = fast_sigmoid(gib[j] + ghb[j]);
    float z = fast_sigmoid(gib[NH + j] + ghb[NH + j]);
    float n = fast_tanh(gib[2 * NH + j] + r * ghb[2 * NH + j]);
    out[idx] = (1.0f - z) * n + z * h[idx];
}

extern "C" void kernel_launch(void* const* d_in, const int* in_sizes, int n_in,
                              void* d_out, int out_size, void* d_ws, size_t ws_size,
                              hipStream_t stream) {
    const float* feats = (const float*)d_in[0];
    const float* h     = (const float*)d_in[1];
    const float* emb   = (const float*)d_in[2];
    const float* w_i2h = (const float*)d_in[3];
    const float* w_h2h = (const float*)d_in[4];
    const float* b_h2h = (const float*)d_in[5];
    const float* w_sc  = (const float*)d_in[6];
    const float* w_ih  = (const float*)d_in[7];
    const float* w_hh  = (const float*)d_in[8];
    const float* b_ih  = (const float*)d_in[9];
    const float* b_hh  = (const float*)d_in[10];
    float* out = (float*)d_out;

    char* ws = (char*)d_ws;
    bf16*  Wfrag   = (bf16*)(ws);                 // 524288 (frag-major image)
    bf16*  w_h2h_b = (bf16*)(ws + 524288);        // 524288
    bf16*  w_ih_b  = (bf16*)(ws + 1048576);       // 2359296
    bf16*  w_hh_b  = (bf16*)(ws + 3407872);       // 1572864
    bf16*  h_b     = (bf16*)(ws + 4980736);       // 262144
    bf16*  x_b     = (bf16*)(ws + 5242880);       // 393216
    float* hT      = (float*)(ws + 5636096);      // 524288 (h_ transposed [512][256])
    float* emit_p  = (float*)(ws + 6160384);      // 524288 (2 slab partials)
    float* alpha   = (float*)(ws + 6684672);      // 262144
    float* gi      = (float*)(ws + 6946816);      // 1572864
    float* gh      = (float*)(ws + 8519680);      // 1572864  -> total 10092544

    // 1) weight/h conversions (w_i2h -> frag-major Wfrag)
    cvt_weights<<<1024, 256, 0, stream>>>(w_i2h, w_h2h, w_ih, w_hh, h,
                                          Wfrag, w_h2h_b, w_ih_b, w_hh_b, h_b);

    // 2) hT = (h @ w_h2h^T + b_h2h)^T ; gh = h @ w_hh^T + b_hh
    gemm_bias<<<dim3(8, 4), 256, 0, stream>>>(h_b, w_h2h_b, b_h2h, hT, 256, NH, NH, 1);
    gemm_bias<<<dim3(24, 4), 256, 0, stream>>>(h_b, w_hh_b, b_hh, gh, 256, NG, NH, 0);

    // 3) fused emit (swapped operands, f32 DMA windows)
    emit_kernel<<<256, 512, 0, stream>>>(feats, Wfrag, hT, w_sc, emit_p);

    // 4) alpha = softmax_T(sum of 2 partials); also output 1
    softmax_t<<<256, 256, 0, stream>>>(emit_p, alpha, out + 131072);

    // 5) context + x build (fused, f32 feats from L3)
    ctx_kernel<<<256, 256, 0, stream>>>(feats, alpha, emb, x_b);

    // 6) gi = x @ w_ih^T + b_ih
    gemm_bias<<<dim3(24, 4), 256, 0, stream>>>(x_b, w_ih_b, b_ih, gi, 256, NG, NX, 0);

    // 7) GRU -> nh (output 0)
    gru_kernel<<<512, 256, 0, stream>>>(gi, gh, h, out);
}